// Round 3
// baseline (244.598 us; speedup 1.0000x reference)
//
#include <hip/hip_runtime.h>

// Integrate-and-fire, soft reset, T=128 sequential scan per row. rows = 262144.
//
// Round-2 postmortem: 3-phase __syncthreads structure = latency-bound (VALUBusy
// 5.9%, HBM 30%). Fix: single-wave blocks (no cross-wave barriers), async
// global_load_lds (width 16) double-buffered with COUNTED vmcnt waits so 8-16
// loads stay in flight across the whole K... er, T-loop. LDS slots XOR-swizzled
// (slot = r*8 + (s ^ (r&7))) so the scan's ds_read_b128 (64 lanes, one slot of
// each row) spreads across all 32 banks; the swizzle is applied on the GLOBAL
// source address (global_load_lds dest must be linear: base + lane*16).

#define T_STEPS 128
#define TC 32                    // timesteps per chunk
#define ROWS 64                  // one wave per block, one row per lane
#define BUF_F (ROWS * TC)        // 2048 floats = 8 KB per buffer

typedef unsigned int u32;
typedef const __attribute__((address_space(1))) u32 gu32;
typedef __attribute__((address_space(3))) u32 lu32;

// Prefetch chunk c of this block's 64 rows into buf (8 x 1KB DMA).
// Instruction k, lane l fills slot j = k*64 + l  ->  row r = k*8 + (l>>3),
// slot_pos = l&7, t-subslot s = (l&7) ^ (r&7) = (l&7) ^ (l>>3) = s_ln.
__device__ __forceinline__ void pf_chunk(const float* __restrict__ x, float* buf,
                                         int rowbase, int c, int r_off, int s_ln) {
    #pragma unroll
    for (int k = 0; k < 8; ++k) {
        const float* gsrc = x + (size_t)(rowbase + k * 8 + r_off) * T_STEPS
                              + c * TC + s_ln * 4;
        __builtin_amdgcn_global_load_lds((gu32*)gsrc, (lu32*)(buf + k * 256), 16, 0, 0);
    }
}

// Sequential scan of 32 steps for row `lane`, in-place spike write.
// Read order s4=0..7 is t-order; LDS addr = lane*32 + ((s4 ^ (lane&7))<<2).
__device__ __forceinline__ float scan_chunk(float* buf, int lane, float v, float thr) {
    float* base = buf + lane * TC;
    const int rx = lane & 7;
    #pragma unroll
    for (int s4 = 0; s4 < 8; ++s4) {
        float4* p = reinterpret_cast<float4*>(base + ((s4 ^ rx) << 2));
        const float4 xv = *p;
        float4 sp;
        v += xv.x; { const bool f = v >= thr; sp.x = f ? 1.0f : 0.0f; v = f ? v - thr : v; }
        v += xv.y; { const bool f = v >= thr; sp.y = f ? 1.0f : 0.0f; v = f ? v - thr : v; }
        v += xv.z; { const bool f = v >= thr; sp.z = f ? 1.0f : 0.0f; v = f ? v - thr : v; }
        v += xv.w; { const bool f = v >= thr; sp.w = f ? 1.0f : 0.0f; v = f ? v - thr : v; }
        *p = sp;
    }
    return v;
}

// Coalesced spike store: lane reads linear slot j = k*64 + lane (cross-lane),
// which holds row r = k*8 + (lane>>3), t-subslot s_ln (permuted within 128B).
__device__ __forceinline__ void st_chunk(float* __restrict__ spikes, const float* buf,
                                         int rowbase, int c, int lane, int r_off, int s_ln) {
    #pragma unroll
    for (int k = 0; k < 8; ++k) {
        const float4 d = *reinterpret_cast<const float4*>(buf + (k * 64 + lane) * 4);
        *reinterpret_cast<float4*>(spikes + (size_t)(rowbase + k * 8 + r_off) * T_STEPS
                                   + c * TC + s_ln * 4) = d;
    }
}

#define WAIT_VM(n) asm volatile("s_waitcnt vmcnt(" #n ")" ::: "memory")
#define WAIT_LGKM0 asm volatile("s_waitcnt lgkmcnt(0)" ::: "memory")

__global__ __launch_bounds__(64) void if_encoder_kernel(
    const float* __restrict__ x, const float* __restrict__ v0,
    const float* __restrict__ thr_p, float* __restrict__ spikes,
    float* __restrict__ vfin, int nrows)
{
    __shared__ __align__(16) float lds[2 * BUF_F];   // 16 KB -> 10 blocks/CU
    float* buf0 = lds;
    float* buf1 = lds + BUF_F;

    const int lane = threadIdx.x;
    const int rowbase = blockIdx.x * ROWS;
    const int r_off = lane >> 3;
    const int s_ln  = (lane & 7) ^ r_off;

    if (rowbase + ROWS <= nrows) {
        float v = v0[rowbase + lane];         // oldest vm op: never perturbs counts
        const float thr = thr_p[0];

        pf_chunk(x, buf0, rowbase, 0, r_off, s_ln);   // 8 in flight
        pf_chunk(x, buf1, rowbase, 1, r_off, s_ln);   // 16 in flight

        // ---- c = 0 ----  queue: [v0, pf0(8), pf1(8)] -> allow pf1
        WAIT_VM(8);
        v = scan_chunk(buf0, lane, v, thr);
        __syncthreads();                               // 1-wave: ~free, orders LDS
        st_chunk(spikes, buf0, rowbase, 0, lane, r_off, s_ln);
        WAIT_LGKM0;                                    // store-phase ds_reads done
        __builtin_amdgcn_sched_barrier(0);             // pin: DMA must not hoist
        pf_chunk(x, buf0, rowbase, 2, r_off, s_ln);

        // ---- c = 1 ----  queue: [pf1(8), st0(8), pf2(8)] -> allow st0+pf2
        WAIT_VM(16);
        v = scan_chunk(buf1, lane, v, thr);
        __syncthreads();
        st_chunk(spikes, buf1, rowbase, 1, lane, r_off, s_ln);
        WAIT_LGKM0;
        __builtin_amdgcn_sched_barrier(0);
        pf_chunk(x, buf1, rowbase, 3, r_off, s_ln);

        // ---- c = 2 ----  queue: [pf2(8), st1(8), pf3(8)] -> allow st1+pf3
        WAIT_VM(16);
        v = scan_chunk(buf0, lane, v, thr);
        __syncthreads();
        st_chunk(spikes, buf0, rowbase, 2, lane, r_off, s_ln);

        // ---- c = 3 ----  queue: [pf3(8), st2(8)] -> allow st2
        WAIT_VM(8);
        v = scan_chunk(buf1, lane, v, thr);
        __syncthreads();
        st_chunk(spikes, buf1, rowbase, 3, lane, r_off, s_ln);

        vfin[rowbase + lane] = v;
    } else {
        // Tail (unused at 262144 rows, kept for safety): scalar per-row scan.
        const int myrow = rowbase + lane;
        if (myrow < nrows) {
            float v = v0[myrow];
            const float thr = thr_p[0];
            const float* xr = x + (size_t)myrow * T_STEPS;
            float* sr = spikes + (size_t)myrow * T_STEPS;
            for (int t = 0; t < T_STEPS; ++t) {
                v += xr[t];
                const bool f = v >= thr;
                sr[t] = f ? 1.0f : 0.0f;
                v = f ? v - thr : v;
            }
            vfin[myrow] = v;
        }
    }
}

extern "C" void kernel_launch(void* const* d_in, const int* in_sizes, int n_in,
                              void* d_out, int out_size, void* d_ws, size_t ws_size,
                              hipStream_t stream) {
    const float* x     = (const float*)d_in[0];   // input_spikes [64,4096,128]
    const float* v0    = (const float*)d_in[1];   // states [64,4096]
    const float* thr_p = (const float*)d_in[2];   // threshold scalar

    const int nrows = in_sizes[1];                // 262144
    float* spikes = (float*)d_out;
    float* vfin   = (float*)d_out + (size_t)nrows * T_STEPS;

    const int blocks = (nrows + ROWS - 1) / ROWS; // 4096
    if_encoder_kernel<<<blocks, ROWS, 0, stream>>>(x, v0, thr_p, spikes, vfin, nrows);
}